// Round 3
// baseline (94.803 us; speedup 1.0000x reference)
//
#include <hip/hip_runtime.h>

#define BATCH    1024
#define NUM_VARS 2048
#define LEAVES   (2 * NUM_VARS)              // 4096
#define LEVELS   12
#define WIDTH    4096
#define TOTAL    (LEAVES + LEVELS * WIDTH)   // 53248
#define NWORDS   (TOTAL / 32)                // 1664 bitmask words

#define CAP      2048                        // max active nodes (validated S<=CAP)
#define BSLICE   4                           // batch columns per eval block
#define NEVB     (BATCH / BSLICE)            // 256 eval blocks -> every CU
#define ETHR     1024                        // 16 waves per eval block

#define ROWS     (NUM_VARS + CAP)            // 4096 LDS value rows per column
#define LDPAD    1                           // stride%32==1 -> col groups spread all 32 banks
#define LDSTRIDE (ROWS + LDPAD)              // 4097
#define SMEM_BYTES (4 * LDSTRIDE * 4 + CAP * 16 + 64)   // buf + enc + counts ~= 96 KB

#define CH_SMEM  (2 * WIDTH * 16)            // setup: double-buffered child4 level (128 KB)

#define PREF_SPLIT 8                         // prefetch blocks per level (wide + shallow)
#define NPREF      (LEVELS * PREF_SPLIT)     // 96
#define SETUP_GRID (1 + NPREF)

// Child code packing:
//   bits 0..13 : LDS row (0..2047 leaf var v; 2048+slot for node slots)
//   bit 14     : complement (leaf 1-x)
//   bit 20     : op (only in e.x; 0=prod, 1=sum)

// ---------------------------------------------------------------------------
// Setup: block 0 = reachability + record build (serial-critical).
// r3: the 12-round marking chain no longer touches global memory on its
// critical path — child4 for level l-1 is issued into registers at the top
// of level l's iteration and ds_written to a double-buffered LDS copy
// after processing (T14 issue-early/write-late). The chain is LDS-latency.
// Blocks 1..96 still warm LLC for the prologue stage + record build.
// ---------------------------------------------------------------------------
__global__ __launch_bounds__(1024) void setup_kernel(const int4* __restrict__ child4,
                                                     const int*  __restrict__ op_type,
                                                     int4* __restrict__ enc4,
                                                     int*  __restrict__ counts)
{
    const int tid = threadIdx.x;

    if (blockIdx.x >= 1) {
        // ---- LLC warm-up (concurrent with block 0)
        const int seg   = blockIdx.x - 1;                 // 0..95
        const int l     = seg / PREF_SPLIT;
        const int part  = seg % PREF_SPLIT;
        const int cnt   = WIDTH / PREF_SPLIT;             // 512 nodes
        const int base  = l * WIDTH + part * cnt;
        int acc = 0;
        for (int i = tid; i < cnt; i += 1024) {
            const int4 c = child4[base + i];
            acc ^= c.x ^ c.y ^ c.z ^ c.w ^ op_type[base + i];
        }
        asm volatile("" :: "v"(acc));        // keep loads live (no DCE), no store
        return;
    }

    // ---- block 0: reachability + record build ----
    extern __shared__ char ssm[];
    int4 (*ch_s)[WIDTH] = (int4 (*)[WIDTH])ssm;           // 2 x 64 KB staged child4
    __shared__ unsigned int flg[NWORDS];      // 6.5 KB bitmask
    __shared__ int nid[CAP];                  // sorted active node ids
    __shared__ int lvl_cnt[LEVELS], lvl_base[LEVELS];
    __shared__ int total_s;
    const int lane = tid & 63;
    const int wv   = tid >> 6;                // 0..15

    // init flags + stage level 11 into ch_s[1] in one phase
    for (int i = tid; i < NWORDS; i += 1024)
        flg[i] = (i == NWORDS - 1) ? 0x80000000u : 0u;    // root = TOTAL-1
    {
        const int4* src = child4 + (LEVELS - 1) * WIDTH;
        int4* dst = ch_s[(LEVELS - 1) & 1];
        #pragma unroll
        for (int p = 0; p < 4; ++p) dst[tid + p * 1024] = src[tid + p * 1024];
    }
    __syncthreads();

    // backward marking: LDS-only critical path, next level prefetched
    for (int l = LEVELS - 1; l >= 0; --l) {
        // issue next level's loads early (latency hides under this level)
        int4 r0, r1, r2, r3;
        if (l > 0) {
            const int4* src = child4 + (l - 1) * WIDTH;
            r0 = src[tid];        r1 = src[tid + 1024];
            r2 = src[tid + 2048]; r3 = src[tid + 3072];
        }
        // process level l from staged copy
        const int4* cs = ch_s[l & 1];
        const int wbase = 128 * (l + 1);
        const unsigned int fw = flg[wbase + (tid >> 3)];  // one read, 4 bits
        const int sh = (tid & 7) * 4;
        #pragma unroll
        for (int j = 0; j < 4; ++j) {
            if ((fw >> (sh + j)) & 1u) {
                const int4 c = cs[(tid << 2) | j];
                atomicOr(&flg[c.x >> 5], 1u << (c.x & 31));
                atomicOr(&flg[c.y >> 5], 1u << (c.y & 31));
                atomicOr(&flg[c.z >> 5], 1u << (c.z & 31));
                atomicOr(&flg[c.w >> 5], 1u << (c.w & 31));
            }
        }
        // write staged next level (vmcnt drains here, overlapped above)
        if (l > 0) {
            int4* dst = ch_s[(l - 1) & 1];
            dst[tid] = r0;        dst[tid + 1024] = r1;
            dst[tid + 2048] = r2; dst[tid + 3072] = r3;
        }
        __syncthreads();
    }

    // parallel per-level compaction counts (wave wv <-> level wv)
    if (wv < LEVELS) {
        const unsigned int w0 = flg[128 * (wv + 1) + 2 * lane];
        const unsigned int w1 = flg[128 * (wv + 1) + 2 * lane + 1];
        const int pc = __popc(w0) + __popc(w1);
        int scan = pc;
        for (int d = 1; d < 64; d <<= 1) {
            const int up = __shfl_up(scan, d, 64);
            if (lane >= d) scan += up;
        }
        if (lane == 63) lvl_cnt[wv] = scan;
    }
    __syncthreads();
    if (tid == 0) {
        int s = 0;
        for (int l = 0; l < LEVELS; ++l) { lvl_base[l] = s; s += lvl_cnt[l]; }
        total_s = (s < CAP) ? s : CAP;
        for (int l = 0; l < LEVELS; ++l) counts[l] = lvl_cnt[l];
        counts[LEVELS] = total_s;
    }
    __syncthreads();
    if (wv < LEVELS) {                        // write sorted ids
        const unsigned int w0 = flg[128 * (wv + 1) + 2 * lane];
        const unsigned int w1 = flg[128 * (wv + 1) + 2 * lane + 1];
        const int pc = __popc(w0) + __popc(w1);
        int scan = pc;
        for (int d = 1; d < 64; d <<= 1) {
            const int up = __shfl_up(scan, d, 64);
            if (lane >= d) scan += up;
        }
        int base = lvl_base[wv] + scan - pc;
        const int nd0 = LEAVES + wv * WIDTH + 64 * lane;
        unsigned int w = w0;
        while (w) { const int b = __ffs(w) - 1; w &= w - 1;
                    if (base < CAP) nid[base] = nd0 + b;      base++; }
        w = w1;
        while (w) { const int b = __ffs(w) - 1; w &= w - 1;
                    if (base < CAP) nid[base] = nd0 + 32 + b; base++; }
    }
    __syncthreads();

    // one-pass record build; 4-way interleaved branchless binary search
    const int S = total_s;
    for (int slot = tid; slot < S; slot += 1024) {
        const int nd = nid[slot];
        const int4 c = child4[nd - LEAVES];
        const int  o = op_type[nd - LEAVES];
        int lo0 = 0, lo1 = 0, lo2 = 0, lo3 = 0;
        int hi0 = S, hi1 = S, hi2 = S, hi3 = S;
        #pragma unroll
        for (int it = 0; it < 11; ++it) {     // 2^11 >= CAP
            const int m0 = (lo0 + hi0) >> 1, m1 = (lo1 + hi1) >> 1;
            const int m2 = (lo2 + hi2) >> 1, m3 = (lo3 + hi3) >> 1;
            const int n0 = nid[m0], n1 = nid[m1], n2 = nid[m2], n3 = nid[m3];
            if (lo0 < hi0) { if (n0 < c.x) lo0 = m0 + 1; else hi0 = m0; }
            if (lo1 < hi1) { if (n1 < c.y) lo1 = m1 + 1; else hi1 = m1; }
            if (lo2 < hi2) { if (n2 < c.z) lo2 = m2 + 1; else hi2 = m2; }
            if (lo3 < hi3) { if (n3 < c.w) lo3 = m3 + 1; else hi3 = m3; }
        }
        int4 e;
        e.x = (c.x < NUM_VARS) ? c.x : (c.x < LEAVES) ? ((c.x - NUM_VARS) | 0x4000)
                                                      : (NUM_VARS + lo0);
        e.y = (c.y < NUM_VARS) ? c.y : (c.y < LEAVES) ? ((c.y - NUM_VARS) | 0x4000)
                                                      : (NUM_VARS + lo1);
        e.z = (c.z < NUM_VARS) ? c.z : (c.z < LEAVES) ? ((c.z - NUM_VARS) | 0x4000)
                                                      : (NUM_VARS + lo2);
        e.w = (c.w < NUM_VARS) ? c.w : (c.w < LEAVES) ? ((c.w - NUM_VARS) | 0x4000)
                                                      : (NUM_VARS + lo3);
        e.x |= o << 20;
        enc4[slot] = e;
    }
}

// ---------------------------------------------------------------------------
// Evaluation: block b owns batch columns [b*4, b*4+4). The ENTIRE value
// state lives in LDS: buf[c][0..2047] = leaf vars for column c (read
// straight from x), buf[c][2048+slot] = node values. All gathers are LDS
// reads; __syncthreads gives level ordering for free. 256 blocks -> one
// per CU, 16 waves each.
// ---------------------------------------------------------------------------
__global__ __launch_bounds__(ETHR) void eval_kernel(const float* __restrict__ x,
                                                    const int4* __restrict__ enc4g,
                                                    const int*  __restrict__ countsg,
                                                    float* __restrict__ out)
{
    extern __shared__ char smem[];
    float* buf      = (float*)smem;                                   // 4*LDSTRIDE f32
    int4*  enc_s    = (int4*)(smem + 4 * LDSTRIDE * sizeof(float));   // CAP int4
    int*   counts_s = (int*)(smem + 4 * LDSTRIDE * sizeof(float) + CAP * sizeof(int4));

    const int tid = threadIdx.x;

    // ---- leaf preload: buf[c][v] = x[(blk*4+c)][v]  (coalesced 256B/wave reads,
    //      consecutive-v LDS writes -> conflict-free)
    {
        const int c  = tid >> 8;              // 0..3
        const int v0 = tid & 255;
        const float* xr = x + (size_t)(blockIdx.x * BSLICE + c) * NUM_VARS;
        float* br = buf + c * LDSTRIDE;
        #pragma unroll
        for (int k = 0; k < NUM_VARS / 256; ++k)
            br[v0 + k * 256] = xr[v0 + k * 256];
    }
    // ---- record + count preload (enc beyond S is never dereferenced)
    #pragma unroll
    for (int i = tid; i < CAP; i += ETHR) enc_s[i] = enc4g[i];
    if (tid < LEVELS) counts_s[tid] = countsg[tid];
    __syncthreads();

    const int col = tid & 3;                  // column within block
    const int nl  = tid >> 2;                 // node lane 0..255
    float* bc = buf + col * LDSTRIDE;

    int sb = 0;
    for (int l = 0; l < LEVELS; ++l) {
        const int n = counts_s[l];
        for (int i = nl; i < n; i += ETHR / BSLICE) {
            const int4 e = enc_s[sb + i];     // 4 lanes same addr -> LDS broadcast
            float v0 = bc[e.x & 0x3FFF];
            float v1 = bc[e.y & 0x3FFF];
            float v2 = bc[e.z & 0x3FFF];
            float v3 = bc[e.w & 0x3FFF];
            v0 = (e.x & 0x4000) ? 1.0f - v0 : v0;
            v1 = (e.y & 0x4000) ? 1.0f - v1 : v1;
            v2 = (e.z & 0x4000) ? 1.0f - v2 : v2;
            v3 = (e.w & 0x4000) ? 1.0f - v3 : v3;
            const float p = ((v0 * v1) * v2) * v3;    // np.prod order
            const float s = ((v0 + v1) + v2) + v3;    // np.sum order
            const float r = (e.x & (1 << 20)) ? s : p;
            bc[NUM_VARS + sb + i] = r;
            if (l == LEVELS - 1 && i == n - 1)
                out[blockIdx.x * BSLICE + col] = r;   // root
        }
        __syncthreads();                      // level boundary (LDS-coherent)
        sb += n;
    }
}

extern "C" void kernel_launch(void* const* d_in, const int* in_sizes, int n_in,
                              void* d_out, int out_size, void* d_ws, size_t ws_size,
                              hipStream_t stream)
{
    const float* x       = (const float*)d_in[0];
    const int4*  child4  = (const int4*)d_in[1];
    const int*   op_type = (const int*)d_in[2];
    float*       out     = (float*)d_out;

    char* w = (char*)d_ws;
    int4* enc4   = (int4*)w;  w += (size_t)CAP * sizeof(int4);   // 32 KB
    int*  counts = (int*)w;   w += 64;

    static bool lds_opted = false;
    if (!lds_opted) {
        hipFuncSetAttribute((const void*)eval_kernel,
                            hipFuncAttributeMaxDynamicSharedMemorySize, SMEM_BYTES);
        hipFuncSetAttribute((const void*)setup_kernel,
                            hipFuncAttributeMaxDynamicSharedMemorySize, CH_SMEM);
        lds_opted = true;
    }

    setup_kernel<<<SETUP_GRID, 1024, CH_SMEM, stream>>>(child4, op_type, enc4, counts);
    eval_kernel<<<NEVB, ETHR, SMEM_BYTES, stream>>>(x, enc4, counts, out);
}

// Round 4
// 76.377 us; speedup vs baseline: 1.2413x; 1.2413x over previous
//
#include <hip/hip_runtime.h>

#define BATCH    1024
#define NUM_VARS 2048
#define LEAVES   (2 * NUM_VARS)              // 4096
#define LEVELS   12
#define WIDTH    4096
#define TOTAL    (LEAVES + LEVELS * WIDTH)   // 53248
#define NWORDS   (TOTAL / 32)                // 1664 bitmask words

#define CAP      2048                        // max active nodes (validated S<=CAP)
#define BSLICE   4                           // batch columns per block
#define NEVB     (BATCH / BSLICE)            // 256 blocks -> one per CU
#define ETHR     1024                        // 16 waves per block

#define ROWS     (NUM_VARS + CAP)            // 4096 value rows per column
#define LDSTRIDE 4100                        // %32==4: quad cols distinct banks; cols 16B-aligned

// ---- LDS carve (bytes) -----------------------------------------------------
#define OFF_BUF   0
#define SZ_BUF    (4 * LDSTRIDE * 4)         // 65600: 4 value columns
#define OFF_ENC   (OFF_BUF + SZ_BUF)         // 65600 (16B aligned)
#define SZ_ENC    (CAP * 16)                 // 32768: encoded records
#define OFF_FLG   (OFF_ENC + SZ_ENC)         // 98368
#define SZ_FLG    (NWORDS * 4)               // 6656: reachability bitmask
#define OFF_NID   (OFF_FLG + SZ_FLG)         // 105024
#define SZ_NID    ((CAP + 8) * 4)            // 8224: sorted ids (+8 OOB-read slack)
#define OFF_MISC  (OFF_NID + SZ_NID)         // 113248
#define SMEM_BYTES (OFF_MISC + 128)          // 113376 (~110.7 KB) -> 1 block/CU

// Child code packing:
//   bits 0..13 : LDS row (0..2047 leaf var v; 2048+slot for node slots)
//   bit 14     : complement (leaf 1-x)
//   bit 20     : op (only in e.x; 0=prod, 1=sum)

// ---------------------------------------------------------------------------
// Single fused kernel. Each of 256 blocks owns batch columns [b*4, b*4+4)
// and REDUNDANTLY computes reachability + records in its own LDS (latency-
// bound, ~5 us, fully parallel across CUs; child4 loads are shared ->
// per-XCD L2 hits). r3 lesson: stage only FLAGGED children (~32 KB total),
// never whole levels (768 KB through one CU = bandwidth-serial).
// Leaf x loads issued at entry (float4), consumed after record build (T14).
// ---------------------------------------------------------------------------
__global__ __launch_bounds__(ETHR) void fused_kernel(const float* __restrict__ x,
                                                     const int4* __restrict__ child4,
                                                     const int*  __restrict__ op_type,
                                                     float* __restrict__ out)
{
    extern __shared__ char smem[];
    float*        buf      = (float*)(smem + OFF_BUF);
    int4*         enc_s    = (int4*)(smem + OFF_ENC);
    unsigned int* flg      = (unsigned int*)(smem + OFF_FLG);
    int*          nid      = (int*)(smem + OFF_NID);
    int*          lvl_cnt  = (int*)(smem + OFF_MISC);
    int*          lvl_base = lvl_cnt + LEVELS;
    int*          total_s  = lvl_base + LEVELS;

    const int tid  = threadIdx.x;
    const int lane = tid & 63;
    const int wv   = tid >> 6;                // 0..15

    // ---- T14 issue-early: leaf loads in flight through the whole setup phase
    const int pc_ = tid >> 8;                 // column 0..3
    const int pq  = tid & 255;
    const float4* xr4 =
        (const float4*)(x + (size_t)(blockIdx.x * BSLICE + pc_) * NUM_VARS);
    const float4 lf0 = xr4[pq];
    const float4 lf1 = xr4[pq + 256];

    // ---- flags init + root bit
    for (int i = tid; i < NWORDS; i += ETHR)
        flg[i] = (i == NWORDS - 1) ? 0x80000000u : 0u;    // root = TOTAL-1
    __syncthreads();

    // ---- backward marking: 12 serial rounds, flagged scattered loads only
    for (int l = LEVELS - 1; l >= 0; --l) {
        const int wbase = 128 * (l + 1);
        const unsigned int fw = flg[wbase + (tid >> 3)];  // one read, 4 node bits
        const int sh = (tid & 7) * 4;
        #pragma unroll
        for (int j = 0; j < 4; ++j) {
            if ((fw >> (sh + j)) & 1u) {
                const int4 c = child4[l * WIDTH + ((tid << 2) | j)];
                atomicOr(&flg[c.x >> 5], 1u << (c.x & 31));
                atomicOr(&flg[c.y >> 5], 1u << (c.y & 31));
                atomicOr(&flg[c.z >> 5], 1u << (c.z & 31));
                atomicOr(&flg[c.w >> 5], 1u << (c.w & 31));
            }
        }
        __syncthreads();
    }

    // ---- per-level counts (wave wv <-> level wv)
    if (wv < LEVELS) {
        const unsigned int w0 = flg[128 * (wv + 1) + 2 * lane];
        const unsigned int w1 = flg[128 * (wv + 1) + 2 * lane + 1];
        const int pc = __popc(w0) + __popc(w1);
        int scan = pc;
        for (int d = 1; d < 64; d <<= 1) {
            const int up = __shfl_up(scan, d, 64);
            if (lane >= d) scan += up;
        }
        if (lane == 63) lvl_cnt[wv] = scan;
    }
    __syncthreads();
    if (tid == 0) {
        int s = 0;
        for (int l = 0; l < LEVELS; ++l) { lvl_base[l] = s; s += lvl_cnt[l]; }
        *total_s = (s < CAP) ? s : CAP;
    }
    __syncthreads();

    // ---- write sorted active ids
    if (wv < LEVELS) {
        const unsigned int w0 = flg[128 * (wv + 1) + 2 * lane];
        const unsigned int w1 = flg[128 * (wv + 1) + 2 * lane + 1];
        const int pc = __popc(w0) + __popc(w1);
        int scan = pc;
        for (int d = 1; d < 64; d <<= 1) {
            const int up = __shfl_up(scan, d, 64);
            if (lane >= d) scan += up;
        }
        int base = lvl_base[wv] + scan - pc;
        const int nd0 = LEAVES + wv * WIDTH + 64 * lane;
        unsigned int w = w0;
        while (w) { const int b = __ffs(w) - 1; w &= w - 1;
                    if (base < CAP) nid[base] = nd0 + b;      base++; }
        w = w1;
        while (w) { const int b = __ffs(w) - 1; w &= w - 1;
                    if (base < CAP) nid[base] = nd0 + 32 + b; base++; }
    }
    __syncthreads();

    // ---- record build into LDS enc_s; 4-way interleaved binary search
    const int S = *total_s;
    for (int slot = tid; slot < S; slot += ETHR) {
        const int nd = nid[slot];
        const int4 c = child4[nd - LEAVES];
        const int  o = op_type[nd - LEAVES];
        int lo0 = 0, lo1 = 0, lo2 = 0, lo3 = 0;
        int hi0 = S, hi1 = S, hi2 = S, hi3 = S;
        #pragma unroll
        for (int it = 0; it < 11; ++it) {     // 2^11 >= CAP
            const int m0 = (lo0 + hi0) >> 1, m1 = (lo1 + hi1) >> 1;
            const int m2 = (lo2 + hi2) >> 1, m3 = (lo3 + hi3) >> 1;
            const int n0 = nid[m0], n1 = nid[m1], n2 = nid[m2], n3 = nid[m3];
            if (lo0 < hi0) { if (n0 < c.x) lo0 = m0 + 1; else hi0 = m0; }
            if (lo1 < hi1) { if (n1 < c.y) lo1 = m1 + 1; else hi1 = m1; }
            if (lo2 < hi2) { if (n2 < c.z) lo2 = m2 + 1; else hi2 = m2; }
            if (lo3 < hi3) { if (n3 < c.w) lo3 = m3 + 1; else hi3 = m3; }
        }
        int4 e;
        e.x = (c.x < NUM_VARS) ? c.x : (c.x < LEAVES) ? ((c.x - NUM_VARS) | 0x4000)
                                                      : (NUM_VARS + lo0);
        e.y = (c.y < NUM_VARS) ? c.y : (c.y < LEAVES) ? ((c.y - NUM_VARS) | 0x4000)
                                                      : (NUM_VARS + lo1);
        e.z = (c.z < NUM_VARS) ? c.z : (c.z < LEAVES) ? ((c.z - NUM_VARS) | 0x4000)
                                                      : (NUM_VARS + lo2);
        e.w = (c.w < NUM_VARS) ? c.w : (c.w < LEAVES) ? ((c.w - NUM_VARS) | 0x4000)
                                                      : (NUM_VARS + lo3);
        e.x |= o << 20;
        enc_s[slot] = e;
    }

    // ---- leaf write (loads issued at entry; latency long since hidden)
    {
        float* br = buf + pc_ * LDSTRIDE;     // column base: 16400 B -> 16B aligned
        ((float4*)br)[pq]       = lf0;
        ((float4*)br)[pq + 256] = lf1;
    }
    __syncthreads();

    // ---- evaluation: all gathers in LDS
    const int col = tid & 3;                  // column within block
    const int nl  = tid >> 2;                 // node lane 0..255
    float* bc = buf + col * LDSTRIDE;

    for (int l = 0; l < LEVELS; ++l) {
        const int n  = lvl_cnt[l];
        const int sb = lvl_base[l];
        for (int i = nl; i < n; i += ETHR / BSLICE) {
            const int4 e = enc_s[sb + i];     // 4 lanes same addr -> LDS broadcast
            float v0 = bc[e.x & 0x3FFF];
            float v1 = bc[e.y & 0x3FFF];
            float v2 = bc[e.z & 0x3FFF];
            float v3 = bc[e.w & 0x3FFF];
            v0 = (e.x & 0x4000) ? 1.0f - v0 : v0;
            v1 = (e.y & 0x4000) ? 1.0f - v1 : v1;
            v2 = (e.z & 0x4000) ? 1.0f - v2 : v2;
            v3 = (e.w & 0x4000) ? 1.0f - v3 : v3;
            const float p = ((v0 * v1) * v2) * v3;    // np.prod order
            const float s = ((v0 + v1) + v2) + v3;    // np.sum order
            const float r = (e.x & (1 << 20)) ? s : p;
            bc[NUM_VARS + sb + i] = r;
            if (l == LEVELS - 1 && i == n - 1)
                out[blockIdx.x * BSLICE + col] = r;   // root
        }
        __syncthreads();                      // level boundary
    }
}

extern "C" void kernel_launch(void* const* d_in, const int* in_sizes, int n_in,
                              void* d_out, int out_size, void* d_ws, size_t ws_size,
                              hipStream_t stream)
{
    const float* x       = (const float*)d_in[0];
    const int4*  child4  = (const int4*)d_in[1];
    const int*   op_type = (const int*)d_in[2];
    float*       out     = (float*)d_out;
    (void)d_ws; (void)ws_size;

    static bool lds_opted = false;
    if (!lds_opted) {
        hipFuncSetAttribute((const void*)fused_kernel,
                            hipFuncAttributeMaxDynamicSharedMemorySize, SMEM_BYTES);
        lds_opted = true;
    }

    fused_kernel<<<NEVB, ETHR, SMEM_BYTES, stream>>>(x, child4, op_type, out);
}

// Round 5
// 75.349 us; speedup vs baseline: 1.2582x; 1.0136x over previous
//
#include <hip/hip_runtime.h>

#define BATCH    1024
#define NUM_VARS 2048
#define LEAVES   (2 * NUM_VARS)              // 4096
#define LEVELS   12
#define WIDTH    4096
#define TOTAL    (LEAVES + LEVELS * WIDTH)   // 53248
#define NWORDS   (TOTAL / 32)                // 1664 bitmask words
#define NNWORDS  (NWORDS - 128)              // 1536 node-only words (levels)

#define CAP      2048                        // max active nodes (validated S<=CAP)
#define BSLICE   4                           // batch columns per block
#define NEVB     (BATCH / BSLICE)            // 256 blocks -> one per CU
#define ETHR     1024                        // 16 waves per block

#define ROWS     (NUM_VARS + CAP)            // 4096 value rows per column
#define LDSTRIDE 4100                        // %32==4: quad cols distinct banks; cols 16B-aligned

// ---- LDS carve (bytes) -----------------------------------------------------
#define OFF_BUF   0
#define SZ_BUF    (4 * LDSTRIDE * 4)         // 65600: 4 value columns
#define OFF_ENC   (OFF_BUF + SZ_BUF)         // 65600 (16B aligned)
#define SZ_ENC    (CAP * 16)                 // 32768: encoded records
#define OFF_FLG   (OFF_ENC + SZ_ENC)         // 98368
#define SZ_FLG    (NWORDS * 4)               // 6656: reachability bitmask
#define OFF_NID   (OFF_FLG + SZ_FLG)         // 105024
#define SZ_NID    ((CAP + 8) * 4)            // 8224: sorted ids (+8 OOB slack)
#define OFF_WSC   (OFF_NID + SZ_NID)         // 113248
#define SZ_WSC    (NNWORDS * 4)              // 6144: word-rank table (O(1) slot lookup)
#define OFF_MISC  (OFF_WSC + SZ_WSC)         // 119392
#define SMEM_BYTES (OFF_MISC + 128)          // ~116.7 KB -> 1 block/CU

// child4 warm slice per CU: 768 KB / 32 CUs-per-XCD = 1536 int4
#define WARM_N   1536

// Child code packing:
//   bits 0..13 : LDS row (0..2047 leaf var v; 2048+slot for node slots)
//   bit 14     : complement (leaf 1-x)
//   bit 20     : op (only in e.x; 0=prod, 1=sum)

// ---------------------------------------------------------------------------
// Single fused kernel; every block redundantly computes reachability +
// records in LDS, then evaluates its 4 batch columns entirely in LDS.
// r4 lesson: the 12-round marking chain dominates; each level must cost
// ONE warm-L2 round-trip, not k serial cold-HBM ones. Hence (1) all 4
// child loads issued unconditionally with predicated addresses, (2) each
// block pre-warms 1/32 of child4 into its XCD's L2 (blockIdx>>3 slice),
// (3) binary search replaced by popcount-rank table.
// ---------------------------------------------------------------------------
__global__ __launch_bounds__(ETHR) void fused_kernel(const float* __restrict__ x,
                                                     const int4* __restrict__ child4,
                                                     const int*  __restrict__ op_type,
                                                     float* __restrict__ out)
{
    extern __shared__ char smem[];
    float*        buf      = (float*)(smem + OFF_BUF);
    int4*         enc_s    = (int4*)(smem + OFF_ENC);
    unsigned int* flg      = (unsigned int*)(smem + OFF_FLG);
    int*          nid      = (int*)(smem + OFF_NID);
    int*          wscan    = (int*)(smem + OFF_WSC);
    int*          lvl_cnt  = (int*)(smem + OFF_MISC);
    int*          lvl_base = lvl_cnt + LEVELS;
    int*          total_s  = lvl_base + LEVELS;

    const int tid  = threadIdx.x;
    const int lane = tid & 63;
    const int wv   = tid >> 6;                // 0..15

    // ---- issue x loads + child4 L2-warm slice (all in flight through init)
    const int pc_ = tid >> 8;                 // column 0..3
    const int pq  = tid & 255;
    const float4* xr4 =
        (const float4*)(x + (size_t)(blockIdx.x * BSLICE + pc_) * NUM_VARS);
    const float4 lf0 = xr4[pq];
    const float4 lf1 = xr4[pq + 256];
    {
        const int seg = (blockIdx.x >> 3) & 31;           // intra-XCD slice id
        const int4 w0 = child4[seg * WARM_N + tid];
        int acc = w0.x ^ w0.y ^ w0.z ^ w0.w;
        if (tid < WARM_N - 1024) {
            const int4 w1 = child4[seg * WARM_N + 1024 + tid];
            acc ^= w1.x ^ w1.y ^ w1.z ^ w1.w;
        }
        asm volatile("" :: "v"(acc));         // keep warm loads live, no store
    }

    // ---- flags init + root bit (overlaps in-flight loads)
    for (int i = tid; i < NWORDS; i += ETHR)
        flg[i] = (i == NWORDS - 1) ? 0x80000000u : 0u;    // root = TOTAL-1

    // ---- leaf write to LDS (waits on x loads only)
    {
        float* br = buf + pc_ * LDSTRIDE;     // column base 16400 B: 16B-aligned
        ((float4*)br)[pq]       = lf0;
        ((float4*)br)[pq + 256] = lf1;
    }
    __syncthreads();                          // drains warm loads too (intended)

    // ---- backward marking: ONE overlapped load round per level per thread
    for (int l = LEVELS - 1; l >= 0; --l) {
        const int wbase = 128 * (l + 1);
        const unsigned int fw = flg[wbase + (tid >> 3)];  // one read, 4 node bits
        const int sh = (tid & 7) * 4;
        int4 c0, c1, c2, c3;
        {   // predicated addresses: unflagged lanes hit line 0 (L1 broadcast)
            const int b = l * WIDTH + (tid << 2);
            c0 = child4[((fw >> (sh + 0)) & 1u) ? b + 0 : 0];
            c1 = child4[((fw >> (sh + 1)) & 1u) ? b + 1 : 0];
            c2 = child4[((fw >> (sh + 2)) & 1u) ? b + 2 : 0];
            c3 = child4[((fw >> (sh + 3)) & 1u) ? b + 3 : 0];
        }
        if ((fw >> (sh + 0)) & 1u) {
            atomicOr(&flg[c0.x >> 5], 1u << (c0.x & 31));
            atomicOr(&flg[c0.y >> 5], 1u << (c0.y & 31));
            atomicOr(&flg[c0.z >> 5], 1u << (c0.z & 31));
            atomicOr(&flg[c0.w >> 5], 1u << (c0.w & 31));
        }
        if ((fw >> (sh + 1)) & 1u) {
            atomicOr(&flg[c1.x >> 5], 1u << (c1.x & 31));
            atomicOr(&flg[c1.y >> 5], 1u << (c1.y & 31));
            atomicOr(&flg[c1.z >> 5], 1u << (c1.z & 31));
            atomicOr(&flg[c1.w >> 5], 1u << (c1.w & 31));
        }
        if ((fw >> (sh + 2)) & 1u) {
            atomicOr(&flg[c2.x >> 5], 1u << (c2.x & 31));
            atomicOr(&flg[c2.y >> 5], 1u << (c2.y & 31));
            atomicOr(&flg[c2.z >> 5], 1u << (c2.z & 31));
            atomicOr(&flg[c2.w >> 5], 1u << (c2.w & 31));
        }
        if ((fw >> (sh + 3)) & 1u) {
            atomicOr(&flg[c3.x >> 5], 1u << (c3.x & 31));
            atomicOr(&flg[c3.y >> 5], 1u << (c3.y & 31));
            atomicOr(&flg[c3.z >> 5], 1u << (c3.z & 31));
            atomicOr(&flg[c3.w >> 5], 1u << (c3.w & 31));
        }
        __syncthreads();
    }

    // ---- per-level counts (wave wv <-> level wv)
    if (wv < LEVELS) {
        const unsigned int w0 = flg[128 * (wv + 1) + 2 * lane];
        const unsigned int w1 = flg[128 * (wv + 1) + 2 * lane + 1];
        const int pc = __popc(w0) + __popc(w1);
        int scan = pc;
        for (int d = 1; d < 64; d <<= 1) {
            const int up = __shfl_up(scan, d, 64);
            if (lane >= d) scan += up;
        }
        if (lane == 63) lvl_cnt[wv] = scan;
    }
    __syncthreads();
    if (tid == 0) {
        int s = 0;
        for (int l = 0; l < LEVELS; ++l) { lvl_base[l] = s; s += lvl_cnt[l]; }
        *total_s = (s < CAP) ? s : CAP;
    }
    __syncthreads();

    // ---- write sorted active ids + word-rank table (absolute slot base/word)
    if (wv < LEVELS) {
        const unsigned int w0 = flg[128 * (wv + 1) + 2 * lane];
        const unsigned int w1 = flg[128 * (wv + 1) + 2 * lane + 1];
        const int pc = __popc(w0) + __popc(w1);
        int scan = pc;
        for (int d = 1; d < 64; d <<= 1) {
            const int up = __shfl_up(scan, d, 64);
            if (lane >= d) scan += up;
        }
        int base = lvl_base[wv] + scan - pc;
        wscan[128 * wv + 2 * lane]     = base;
        wscan[128 * wv + 2 * lane + 1] = base + __popc(w0);
        const int nd0 = LEAVES + wv * WIDTH + 64 * lane;
        unsigned int w = w0;
        while (w) { const int b = __ffs(w) - 1; w &= w - 1;
                    if (base < CAP) nid[base] = nd0 + b;      base++; }
        w = w1;
        while (w) { const int b = __ffs(w) - 1; w &= w - 1;
                    if (base < CAP) nid[base] = nd0 + 32 + b; base++; }
    }
    __syncthreads();

    // ---- record build into LDS enc_s; O(1) popcount-rank slot lookup
    const int S = *total_s;
    for (int slot = tid; slot < S; slot += ETHR) {
        const int nd = nid[slot];
        const int4 c = child4[nd - LEAVES];
        const int  o = op_type[nd - LEAVES];
        int4 e;
        {
            const int cc = c.x;
            const int w  = cc >> 5;
            const int r  = (cc >= LEAVES)
                ? NUM_VARS + wscan[w - 128] + __popc(flg[w] & ((1u << (cc & 31)) - 1))
                : (cc < NUM_VARS ? cc : (cc - NUM_VARS) | 0x4000);
            e.x = r;
        }
        {
            const int cc = c.y;
            const int w  = cc >> 5;
            e.y = (cc >= LEAVES)
                ? NUM_VARS + wscan[w - 128] + __popc(flg[w] & ((1u << (cc & 31)) - 1))
                : (cc < NUM_VARS ? cc : (cc - NUM_VARS) | 0x4000);
        }
        {
            const int cc = c.z;
            const int w  = cc >> 5;
            e.z = (cc >= LEAVES)
                ? NUM_VARS + wscan[w - 128] + __popc(flg[w] & ((1u << (cc & 31)) - 1))
                : (cc < NUM_VARS ? cc : (cc - NUM_VARS) | 0x4000);
        }
        {
            const int cc = c.w;
            const int w  = cc >> 5;
            e.w = (cc >= LEAVES)
                ? NUM_VARS + wscan[w - 128] + __popc(flg[w] & ((1u << (cc & 31)) - 1))
                : (cc < NUM_VARS ? cc : (cc - NUM_VARS) | 0x4000);
        }
        e.x |= o << 20;
        enc_s[slot] = e;
    }
    __syncthreads();

    // ---- evaluation: all gathers in LDS
    const int col = tid & 3;                  // column within block
    const int nl  = tid >> 2;                 // node lane 0..255
    float* bc = buf + col * LDSTRIDE;

    for (int l = 0; l < LEVELS; ++l) {
        const int n  = lvl_cnt[l];
        const int sb = lvl_base[l];
        for (int i = nl; i < n; i += ETHR / BSLICE) {
            const int4 e = enc_s[sb + i];     // 4 lanes same addr -> LDS broadcast
            float v0 = bc[e.x & 0x3FFF];
            float v1 = bc[e.y & 0x3FFF];
            float v2 = bc[e.z & 0x3FFF];
            float v3 = bc[e.w & 0x3FFF];
            v0 = (e.x & 0x4000) ? 1.0f - v0 : v0;
            v1 = (e.y & 0x4000) ? 1.0f - v1 : v1;
            v2 = (e.z & 0x4000) ? 1.0f - v2 : v2;
            v3 = (e.w & 0x4000) ? 1.0f - v3 : v3;
            const float p = ((v0 * v1) * v2) * v3;    // np.prod order
            const float s = ((v0 + v1) + v2) + v3;    // np.sum order
            const float r = (e.x & (1 << 20)) ? s : p;
            bc[NUM_VARS + sb + i] = r;
            if (l == LEVELS - 1 && i == n - 1)
                out[blockIdx.x * BSLICE + col] = r;   // root
        }
        __syncthreads();                      // level boundary
    }
}

extern "C" void kernel_launch(void* const* d_in, const int* in_sizes, int n_in,
                              void* d_out, int out_size, void* d_ws, size_t ws_size,
                              hipStream_t stream)
{
    const float* x       = (const float*)d_in[0];
    const int4*  child4  = (const int4*)d_in[1];
    const int*   op_type = (const int*)d_in[2];
    float*       out     = (float*)d_out;
    (void)d_ws; (void)ws_size;

    static bool lds_opted = false;
    if (!lds_opted) {
        hipFuncSetAttribute((const void*)fused_kernel,
                            hipFuncAttributeMaxDynamicSharedMemorySize, SMEM_BYTES);
        lds_opted = true;
    }

    fused_kernel<<<NEVB, ETHR, SMEM_BYTES, stream>>>(x, child4, op_type, out);
}